// Round 7
// baseline (283.237 us; speedup 1.0000x reference)
//
#include <hip/hip_runtime.h>
#include <hip/hip_bf16.h>
#include <math.h>

// MHA: B=2,S=2048,E=1024,H=16,Dk=64. fp32 in/out, bf16 MFMA internally.
// cvt_w: 4 weights fp32->bf16. cvt_x: activation fp32->bf16 (shared buf, serial).
// gemm64<MODE>: 64x128 tile, BK=64, ping-pong LDS (1 barrier/iter),
//   both operands via swizzled global_load_lds. scale folds softmax 1/8*log2e
//   into Q. MODE 0: fp32+bias; 1: bf16 [B][H][S][Dk]; 2: bf16 [B][H][Dk][S].
// attn: S^T-MFMA flash, exp2-softmax (scale pre-folded), l via ones-MFMA,
//   64 q/block (16/wave), ping-pong K/V, 1 barrier/iter.

constexpr int Sn = 2048;
constexpr int En = 1024;
constexpr int Hn = 16;
constexpr int Dk = 64;
constexpr int Kn = 1024;
constexpr size_t WSZ = 1048576;
constexpr size_t TSZ = 4194304;
constexpr int PST = 72;           // Ps row stride (bf16)

typedef __bf16 bf16x8 __attribute__((ext_vector_type(8)));
typedef float  f32x4  __attribute__((ext_vector_type(4)));

union U16 { uint4 u; bf16x8 v; __hip_bfloat16 h[8]; };
union U8  { uint2 u; __hip_bfloat162 h2[2]; __hip_bfloat16 h[4]; };

__device__ inline U16 cvt8f(const float* __restrict__ p) {
    float4 a = *(const float4*)p;
    float4 b = *(const float4*)(p + 4);
    U16 r;
    r.h[0] = __float2bfloat16(a.x); r.h[1] = __float2bfloat16(a.y);
    r.h[2] = __float2bfloat16(a.z); r.h[3] = __float2bfloat16(a.w);
    r.h[4] = __float2bfloat16(b.x); r.h[5] = __float2bfloat16(b.y);
    r.h[6] = __float2bfloat16(b.z); r.h[7] = __float2bfloat16(b.w);
    return r;
}

__device__ inline void gload16(const __hip_bfloat16* g, __hip_bfloat16* l) {
    __builtin_amdgcn_global_load_lds(
        (const __attribute__((address_space(1))) void*)g,
        (__attribute__((address_space(3))) void*)l, 16, 0, 0);
}

// Stage ROWS x 64 bf16 tile via global_load_lds, XOR-swizzled.
template<int ROWS, int NW>
__device__ inline void stage_tile(const __hip_bfloat16* __restrict__ src, int ld,
                                  __hip_bfloat16* lds, int w, int lane) {
    int l8 = lane >> 3;
    int g = (lane & 7) ^ (l8 & 7);
    #pragma unroll
    for (int j = 0; j < ROWS / (8 * NW); ++j) {
        int c = j * NW + w;
        gload16(src + (size_t)(c * 8 + l8) * ld + g * 8, lds + c * 512);
    }
}

// ---------------- converts ----------------
__global__ __launch_bounds__(256)
void cvt_w(const float* __restrict__ w0, const float* __restrict__ w1,
           const float* __restrict__ w2, const float* __restrict__ w3,
           __hip_bfloat16* __restrict__ dst)
{
    int y = blockIdx.y;
    const float* src = (y == 0) ? w0 : (y == 1) ? w1 : (y == 2) ? w2 : w3;
    size_t i = ((size_t)blockIdx.x * 256 + threadIdx.x) * 8;
    U16 r = cvt8f(src + i);
    *(uint4*)&dst[(size_t)y * WSZ + i] = r.u;
}

__global__ __launch_bounds__(256)
void cvt_x(const float* __restrict__ src, __hip_bfloat16* __restrict__ dst)
{
    size_t i = ((size_t)blockIdx.x * 256 + threadIdx.x) * 8;
    U16 r = cvt8f(src + i);
    *(uint4*)&dst[i] = r.u;
}

// ---------------- GEMM: C = (A @ W^T + b) * scale ----------------
// 64x128 tile, BK=64, ping-pong LDS, 4 waves each 32x64 (2x4 frags).
template<int MODE>
__global__ __launch_bounds__(256)
void gemm64(const __hip_bfloat16* __restrict__ A, const __hip_bfloat16* __restrict__ W,
            const float* __restrict__ bias, void* __restrict__ outp, float scale)
{
    __shared__ __align__(16) __hip_bfloat16 As[2][64 * 64];
    __shared__ __align__(16) __hip_bfloat16 Bs[2][128 * 64];

    const int tid = threadIdx.x, w = tid >> 6, lane = tid & 63;
    const int l15 = lane & 15, lg = lane >> 4, l7 = lane & 7;
    const int blockM = blockIdx.x * 64, blockN = blockIdx.y * 128;
    const int wm = (w & 1) * 32, wn = (w >> 1) * 64;
    const int coff0 = (lg ^ l7) * 8;
    const int coff1 = ((4 + lg) ^ l7) * 8;

    f32x4 acc[2][4];
    #pragma unroll
    for (int i = 0; i < 2; ++i)
        #pragma unroll
        for (int j = 0; j < 4; ++j) acc[i][j] = {0.f, 0.f, 0.f, 0.f};

    const __hip_bfloat16* Ab = A + (size_t)blockM * Kn;
    const __hip_bfloat16* Wb = W + (size_t)blockN * Kn;

    stage_tile<64, 4>(Ab, Kn, As[0], w, lane);
    stage_tile<128, 4>(Wb, Kn, Bs[0], w, lane);

    for (int t = 0; t < Kn / 64; ++t) {
        __syncthreads();
        const int cur = t & 1;
        if (t + 1 < Kn / 64) {
            stage_tile<64, 4>(Ab + (t + 1) * 64, Kn, As[cur ^ 1], w, lane);
            stage_tile<128, 4>(Wb + (t + 1) * 64, Kn, Bs[cur ^ 1], w, lane);
        }

        U16 af[2][2], bf[4][2];
        #pragma unroll
        for (int mt = 0; mt < 2; ++mt) {
            int r = (wm + mt * 16 + l15) * 64;
            af[mt][0].u = *(const uint4*)&As[cur][r + coff0];
            af[mt][1].u = *(const uint4*)&As[cur][r + coff1];
        }
        #pragma unroll
        for (int nt = 0; nt < 4; ++nt) {
            int r = (wn + nt * 16 + l15) * 64;
            bf[nt][0].u = *(const uint4*)&Bs[cur][r + coff0];
            bf[nt][1].u = *(const uint4*)&Bs[cur][r + coff1];
        }
        #pragma unroll
        for (int mt = 0; mt < 2; ++mt)
            #pragma unroll
            for (int nt = 0; nt < 4; ++nt) {
                acc[mt][nt] = __builtin_amdgcn_mfma_f32_16x16x32_bf16(af[mt][0].v, bf[nt][0].v, acc[mt][nt], 0, 0, 0);
                acc[mt][nt] = __builtin_amdgcn_mfma_f32_16x16x32_bf16(af[mt][1].v, bf[nt][1].v, acc[mt][nt], 0, 0, 0);
            }
    }

    // epilogue. C/D: col=l15, row=lg*4+i
    #pragma unroll
    for (int nt = 0; nt < 4; ++nt) {
        int n = blockN + wn + nt * 16 + l15;
        float bvn = bias[n];
        int h_ = n >> 6, d_ = n & 63;
        #pragma unroll
        for (int mt = 0; mt < 2; ++mt) {
            int m0 = blockM + wm + mt * 16 + lg * 4;
            if constexpr (MODE == 0) {
                float* out = (float*)outp;
                #pragma unroll
                for (int i = 0; i < 4; ++i)
                    out[(size_t)(m0 + i) * Kn + n] = acc[mt][nt][i] + bvn;
            } else if constexpr (MODE == 1) {
                __hip_bfloat16* out = (__hip_bfloat16*)outp;
                int b_ = m0 >> 11, s_ = m0 & (Sn - 1);
                #pragma unroll
                for (int i = 0; i < 4; ++i)
                    out[(((size_t)b_ * Hn + h_) * Sn + s_ + i) * Dk + d_] =
                        __float2bfloat16((acc[mt][nt][i] + bvn) * scale);
            } else {
                __hip_bfloat16* out = (__hip_bfloat16*)outp;
                int b_ = m0 >> 11, s_ = m0 & (Sn - 1);
                U8 pk;
                #pragma unroll
                for (int i = 0; i < 4; ++i) pk.h[i] = __float2bfloat16(acc[mt][nt][i] + bvn);
                *(uint2*)&out[(((size_t)b_ * Hn + h_) * Dk + d_) * Sn + s_] = pk.u;
            }
        }
    }
}

// ---------------- flash attention ----------------
// 256 thr (4 waves), 64 q/block (16/wave), 64-key tiles, ping-pong, 1 barrier.
// Q pre-scaled by 0.125*log2(e): P = exp2(S'). l via ones-fragment MFMA.
__global__ __launch_bounds__(256)
void attn(const __hip_bfloat16* __restrict__ Q, const __hip_bfloat16* __restrict__ K,
          const __hip_bfloat16* __restrict__ Vt, __hip_bfloat16* __restrict__ X)
{
    __shared__ __align__(16) __hip_bfloat16 Ks[2][64 * 64];
    __shared__ __align__(16) __hip_bfloat16 Vts[2][64 * 64];
    __shared__ __align__(16) __hip_bfloat16 Ps[64 * PST];

    const int bh = blockIdx.y, q0 = blockIdx.x * 64;
    const int tid = threadIdx.x, w = tid >> 6, lane = tid & 63;
    const int l15 = lane & 15, lg = lane >> 4, l7 = lane & 7;
    const int coff0 = (lg ^ l7) * 8;
    const int coff1 = ((4 + lg) ^ l7) * 8;

    const __hip_bfloat16* Qb = Q  + (size_t)bh * Sn * Dk;
    const __hip_bfloat16* Kb = K  + (size_t)bh * Sn * Dk;
    const __hip_bfloat16* Vb = Vt + (size_t)bh * Dk * Sn;

    // ones B-frag in registers: B[n=l15][k]=1 iff n==0 (row of ones)
    U16 onesf;
    {
        __hip_bfloat16 v = (l15 == 0) ? __float2bfloat16(1.0f) : __float2bfloat16(0.0f);
        #pragma unroll
        for (int j = 0; j < 8; ++j) onesf.h[j] = v;
    }

    // Q B-frags (pre-scaled), queries q0 + w*16 + l15
    U16 aq0, aq1;
    {
        const __hip_bfloat16* qp = Qb + (size_t)(q0 + w * 16 + l15) * Dk + lg * 8;
        aq0.u = *(const uint4*)qp;
        aq1.u = *(const uint4*)(qp + 32);
    }

    f32x4 o[5];   // o[0..3]: C[q][d-tile]; o[4]: col0 = l[q]
    #pragma unroll
    for (int dt = 0; dt < 5; ++dt) o[dt] = {0.f, 0.f, 0.f, 0.f};

    __hip_bfloat16* Pw = Ps + (w * 16) * PST;   // wave-private 16 rows

    stage_tile<64, 4>(Kb, Dk, Ks[0], w, lane);
    stage_tile<64, 4>(Vb, Sn, Vts[0], w, lane);

    for (int t = 0; t < Sn / 64; ++t) {
        __syncthreads();
        const int cur = t & 1;
        if (t + 1 < Sn / 64) {
            stage_tile<64, 4>(Kb + (size_t)(t + 1) * 64 * Dk, Dk, Ks[cur ^ 1], w, lane);
            stage_tile<64, 4>(Vb + (t + 1) * 64, Sn, Vts[cur ^ 1], w, lane);
        }

        // S^T = K·Q'^T ; P = exp2(S'); store P[q=l15][key]
        #pragma unroll
        for (int kt = 0; kt < 4; ++kt) {
            int r = (kt * 16 + l15) * 64;
            U16 kf0, kf1;
            kf0.u = *(const uint4*)&Ks[cur][r + coff0];
            kf1.u = *(const uint4*)&Ks[cur][r + coff1];
            f32x4 s = {0.f, 0.f, 0.f, 0.f};
            s = __builtin_amdgcn_mfma_f32_16x16x32_bf16(kf0.v, aq0.v, s, 0, 0, 0);
            s = __builtin_amdgcn_mfma_f32_16x16x32_bf16(kf1.v, aq1.v, s, 0, 0, 0);
            U8 pk;
            pk.h2[0] = __float22bfloat162_rn({exp2f(s[0]), exp2f(s[1])});
            pk.h2[1] = __float22bfloat162_rn({exp2f(s[2]), exp2f(s[3])});
            *(uint2*)&Pw[l15 * PST + kt * 16 + lg * 4] = pk.u;
        }

        // PV + l: A = P row q=l15
        U16 pf0, pf1;
        pf0.u = *(const uint4*)&Pw[l15 * PST + lg * 8];
        pf1.u = *(const uint4*)&Pw[l15 * PST + 32 + lg * 8];
        #pragma unroll
        for (int dt = 0; dt < 4; ++dt) {
            int r = (dt * 16 + l15) * 64;
            U16 v0, v1;
            v0.u = *(const uint4*)&Vts[cur][r + coff0];
            v1.u = *(const uint4*)&Vts[cur][r + coff1];
            o[dt] = __builtin_amdgcn_mfma_f32_16x16x32_bf16(pf0.v, v0.v, o[dt], 0, 0, 0);
            o[dt] = __builtin_amdgcn_mfma_f32_16x16x32_bf16(pf1.v, v1.v, o[dt], 0, 0, 0);
        }
        o[4] = __builtin_amdgcn_mfma_f32_16x16x32_bf16(pf0.v, onesf.v, o[4], 0, 0, 0);
        o[4] = __builtin_amdgcn_mfma_f32_16x16x32_bf16(pf1.v, onesf.v, o[4], 0, 0, 0);
    }

    // l[q=lg*4+i] sits in lanes l15==0 (lane = lg*16); broadcast within group
    float linv[4];
    #pragma unroll
    for (int i = 0; i < 4; ++i)
        linv[i] = 1.f / __shfl(o[4][i], lane & 48, 64);

    int b_ = bh >> 4, h_ = bh & (Hn - 1);
    #pragma unroll
    for (int i = 0; i < 4; ++i) {
        int sr = q0 + w * 16 + lg * 4 + i;
        __hip_bfloat16* xp = X + ((size_t)(b_ * Sn + sr)) * En + h_ * Dk + l15;
        #pragma unroll
        for (int dt = 0; dt < 4; ++dt)
            xp[dt * 16] = __float2bfloat16(o[dt][i] * linv[i]);
    }
}

extern "C" void kernel_launch(void* const* d_in, const int* in_sizes, int n_in,
                              void* d_out, int out_size, void* d_ws, size_t ws_size,
                              hipStream_t stream)
{
    const float* query = (const float*)d_in[0];
    const float* key   = (const float*)d_in[1];
    const float* value = (const float*)d_in[2];
    const float* Wq = (const float*)d_in[3];
    const float* bq = (const float*)d_in[4];
    const float* Wk = (const float*)d_in[5];
    const float* bk = (const float*)d_in[6];
    const float* Wv = (const float*)d_in[7];
    const float* bv = (const float*)d_in[8];
    const float* Wo = (const float*)d_in[9];
    const float* bo = (const float*)d_in[10];
    float* out = (float*)d_out;

    // ws (bf16): xbuf[4M] | Wbf[4M] | Qw[4M] | Kw[4M] | Vtw[4M] = 40 MB.
    __hip_bfloat16* xbuf = (__hip_bfloat16*)d_ws;
    __hip_bfloat16* Wbf  = xbuf + TSZ;
    __hip_bfloat16* Qw   = Wbf + 4 * WSZ;
    __hip_bfloat16* Kw   = Qw + TSZ;
    __hip_bfloat16* Vtw  = Kw + TSZ;
    __hip_bfloat16* Xw   = xbuf;   // attn out aliases xbuf

    const float QSCALE = 0.125f * 1.44269504f;   // fold 1/sqrt(Dk) * log2(e)
    dim3 ggrid(64, 8);

    cvt_w<<<dim3(512, 4), 256, 0, stream>>>(Wq, Wk, Wv, Wo, Wbf);
    cvt_x<<<2048, 256, 0, stream>>>(query, xbuf);
    gemm64<1><<<ggrid, 256, 0, stream>>>(xbuf, Wbf, bq, Qw, QSCALE);
    cvt_x<<<2048, 256, 0, stream>>>(key, xbuf);
    gemm64<1><<<ggrid, 256, 0, stream>>>(xbuf, Wbf + WSZ, bk, Kw, 1.0f);
    cvt_x<<<2048, 256, 0, stream>>>(value, xbuf);
    gemm64<2><<<ggrid, 256, 0, stream>>>(xbuf, Wbf + 2 * WSZ, bv, Vtw, 1.0f);
    attn<<<dim3(Sn / 64, 32), 256, 0, stream>>>(Qw, Kw, Vtw, Xw);
    gemm64<0><<<ggrid, 256, 0, stream>>>(Xw, Wbf + 3 * WSZ, bo, out, 1.0f);
}

// Round 9
// 252.696 us; speedup vs baseline: 1.1209x; 1.1209x over previous
//
#include <hip/hip_runtime.h>
#include <hip/hip_bf16.h>
#include <math.h>

// MHA: B=2,S=2048,E=1024,H=16,Dk=64. fp32 in/out, bf16 MFMA internally.
// cvt_w: 4 weights fp32->bf16. cvt_x: activation fp32->bf16 (shared buf, serial).
// gemm64<MODE>: 64x128 tile, BK=64, single-buffer 2-barrier (24KB LDS),
//   both operands via swizzled global_load_lds.
//   MODE 0: fp32+bias; 1: bf16 [B][H][S][Dk] (*scale); 2: bf16 [B][H][Dk][S].
// attn: S^T-MFMA flash, 128 q/block (32/wave), 64-key tiles, 2-barrier staging
//   (deterministic: no async load state crosses a barrier — R8's 1-barrier
//   ping-pong diverged under graph replay), exp2 softmax (scale pre-folded
//   into Q), l via ones-fragment MFMA.

constexpr int Sn = 2048;
constexpr int En = 1024;
constexpr int Hn = 16;
constexpr int Dk = 64;
constexpr int Kn = 1024;
constexpr size_t WSZ = 1048576;
constexpr size_t TSZ = 4194304;
constexpr int PST = 72;           // Ps row stride (bf16)

typedef __bf16 bf16x8 __attribute__((ext_vector_type(8)));
typedef float  f32x4  __attribute__((ext_vector_type(4)));

union U16 { uint4 u; bf16x8 v; __hip_bfloat16 h[8]; };
union U8  { uint2 u; __hip_bfloat162 h2[2]; __hip_bfloat16 h[4]; };

__device__ inline U16 cvt8f(const float* __restrict__ p) {
    float4 a = *(const float4*)p;
    float4 b = *(const float4*)(p + 4);
    U16 r;
    r.h[0] = __float2bfloat16(a.x); r.h[1] = __float2bfloat16(a.y);
    r.h[2] = __float2bfloat16(a.z); r.h[3] = __float2bfloat16(a.w);
    r.h[4] = __float2bfloat16(b.x); r.h[5] = __float2bfloat16(b.y);
    r.h[6] = __float2bfloat16(b.z); r.h[7] = __float2bfloat16(b.w);
    return r;
}

__device__ inline void gload16(const __hip_bfloat16* g, __hip_bfloat16* l) {
    __builtin_amdgcn_global_load_lds(
        (const __attribute__((address_space(1))) void*)g,
        (__attribute__((address_space(3))) void*)l, 16, 0, 0);
}

// Stage ROWS x 64 bf16 tile via global_load_lds, XOR-swizzled:
// LDS granule p of row r holds global granule p^(r&7). Dest lane-contiguous.
template<int ROWS, int NW>
__device__ inline void stage_tile(const __hip_bfloat16* __restrict__ src, int ld,
                                  __hip_bfloat16* lds, int w, int lane) {
    int l8 = lane >> 3;
    int g = (lane & 7) ^ (l8 & 7);
    #pragma unroll
    for (int j = 0; j < ROWS / (8 * NW); ++j) {
        int c = j * NW + w;
        gload16(src + (size_t)(c * 8 + l8) * ld + g * 8, lds + c * 512);
    }
}

// ---------------- converts ----------------
__global__ __launch_bounds__(256)
void cvt_w(const float* __restrict__ w0, const float* __restrict__ w1,
           const float* __restrict__ w2, const float* __restrict__ w3,
           __hip_bfloat16* __restrict__ dst)
{
    int y = blockIdx.y;
    const float* src = (y == 0) ? w0 : (y == 1) ? w1 : (y == 2) ? w2 : w3;
    size_t i = ((size_t)blockIdx.x * 256 + threadIdx.x) * 8;
    U16 r = cvt8f(src + i);
    *(uint4*)&dst[(size_t)y * WSZ + i] = r.u;
}

__global__ __launch_bounds__(256)
void cvt_x(const float* __restrict__ src, __hip_bfloat16* __restrict__ dst)
{
    size_t i = ((size_t)blockIdx.x * 256 + threadIdx.x) * 8;
    U16 r = cvt8f(src + i);
    *(uint4*)&dst[i] = r.u;
}

// ---------------- GEMM: C = (A @ W^T + b) [*scale] ----------------
// 64x128 tile, BK=64, single-buffer 2-barrier, 4 waves each 32x64 (2x4 frags).
template<int MODE>
__global__ __launch_bounds__(256)
void gemm64(const __hip_bfloat16* __restrict__ A, const __hip_bfloat16* __restrict__ W,
            const float* __restrict__ bias, void* __restrict__ outp, float scale)
{
    __shared__ __align__(16) __hip_bfloat16 As[64 * 64];
    __shared__ __align__(16) __hip_bfloat16 Bs[128 * 64];

    const int tid = threadIdx.x, w = tid >> 6, lane = tid & 63;
    const int l15 = lane & 15, lg = lane >> 4, l7 = lane & 7;
    const int blockM = blockIdx.x * 64, blockN = blockIdx.y * 128;
    const int wm = (w & 1) * 32, wn = (w >> 1) * 64;
    const int coff0 = (lg ^ l7) * 8;
    const int coff1 = ((4 + lg) ^ l7) * 8;

    f32x4 acc[2][4];
    #pragma unroll
    for (int i = 0; i < 2; ++i)
        #pragma unroll
        for (int j = 0; j < 4; ++j) acc[i][j] = {0.f, 0.f, 0.f, 0.f};

    for (int k0 = 0; k0 < Kn; k0 += 64) {
        stage_tile<64, 4>(A + (size_t)blockM * Kn + k0, Kn, As, w, lane);
        stage_tile<128, 4>(W + (size_t)blockN * Kn + k0, Kn, Bs, w, lane);
        __syncthreads();

        U16 af[2][2], bf[4][2];
        #pragma unroll
        for (int mt = 0; mt < 2; ++mt) {
            int r = (wm + mt * 16 + l15) * 64;
            af[mt][0].u = *(const uint4*)&As[r + coff0];
            af[mt][1].u = *(const uint4*)&As[r + coff1];
        }
        #pragma unroll
        for (int nt = 0; nt < 4; ++nt) {
            int r = (wn + nt * 16 + l15) * 64;
            bf[nt][0].u = *(const uint4*)&Bs[r + coff0];
            bf[nt][1].u = *(const uint4*)&Bs[r + coff1];
        }
        #pragma unroll
        for (int mt = 0; mt < 2; ++mt)
            #pragma unroll
            for (int nt = 0; nt < 4; ++nt) {
                acc[mt][nt] = __builtin_amdgcn_mfma_f32_16x16x32_bf16(af[mt][0].v, bf[nt][0].v, acc[mt][nt], 0, 0, 0);
                acc[mt][nt] = __builtin_amdgcn_mfma_f32_16x16x32_bf16(af[mt][1].v, bf[nt][1].v, acc[mt][nt], 0, 0, 0);
            }
        __syncthreads();
    }

    // epilogue. C/D: col=l15, row=lg*4+i
    #pragma unroll
    for (int nt = 0; nt < 4; ++nt) {
        int n = blockN + wn + nt * 16 + l15;
        float bvn = bias[n];
        int h_ = n >> 6, d_ = n & 63;
        #pragma unroll
        for (int mt = 0; mt < 2; ++mt) {
            int m0 = blockM + wm + mt * 16 + lg * 4;
            if constexpr (MODE == 0) {
                float* out = (float*)outp;
                #pragma unroll
                for (int i = 0; i < 4; ++i)
                    out[(size_t)(m0 + i) * Kn + n] = acc[mt][nt][i] + bvn;
            } else if constexpr (MODE == 1) {
                __hip_bfloat16* out = (__hip_bfloat16*)outp;
                int b_ = m0 >> 11, s_ = m0 & (Sn - 1);
                #pragma unroll
                for (int i = 0; i < 4; ++i)
                    out[(((size_t)b_ * Hn + h_) * Sn + s_ + i) * Dk + d_] =
                        __float2bfloat16((acc[mt][nt][i] + bvn) * scale);
            } else {
                __hip_bfloat16* out = (__hip_bfloat16*)outp;
                int b_ = m0 >> 11, s_ = m0 & (Sn - 1);
                U8 pk;
                #pragma unroll
                for (int i = 0; i < 4; ++i) pk.h[i] = __float2bfloat16(acc[mt][nt][i] + bvn);
                *(uint2*)&out[(((size_t)b_ * Hn + h_) * Dk + d_) * Sn + s_] = pk.u;
            }
        }
    }
}

// ---------------- flash attention ----------------
// 256 thr (4 waves), 128 q/block (32/wave, qt=2), 64-key tiles, single K/V
// buffer with 2-barrier staging (deterministic under graph replay).
// Q pre-scaled by 0.125*log2e -> P = exp2(S'). l via ones-fragment MFMA.
__global__ __launch_bounds__(256)
void attn(const __hip_bfloat16* __restrict__ Q, const __hip_bfloat16* __restrict__ K,
          const __hip_bfloat16* __restrict__ Vt, __hip_bfloat16* __restrict__ X)
{
    __shared__ __align__(16) __hip_bfloat16 Ks[64 * 64];
    __shared__ __align__(16) __hip_bfloat16 Vts[64 * 64];
    __shared__ __align__(16) __hip_bfloat16 Ps[128 * PST];

    const int bh = blockIdx.y, q0 = blockIdx.x * 128;
    const int tid = threadIdx.x, w = tid >> 6, lane = tid & 63;
    const int l15 = lane & 15, lg = lane >> 4, l7 = lane & 7;
    const int coff0 = (lg ^ l7) * 8;
    const int coff1 = ((4 + lg) ^ l7) * 8;

    const __hip_bfloat16* Qb = Q  + (size_t)bh * Sn * Dk;
    const __hip_bfloat16* Kb = K  + (size_t)bh * Sn * Dk;
    const __hip_bfloat16* Vb = Vt + (size_t)bh * Dk * Sn;

    // ones B-frag: B[n=l15][k]=1 iff n==0 -> D[q][0] = sum_k P[q][k]
    U16 onesf;
    {
        __hip_bfloat16 v = (l15 == 0) ? __float2bfloat16(1.0f) : __float2bfloat16(0.0f);
        #pragma unroll
        for (int j = 0; j < 8; ++j) onesf.h[j] = v;
    }

    // Q B-frags (pre-scaled), queries q0 + w*32 + qt*16 + l15
    U16 aq[2][2];
    #pragma unroll
    for (int qt = 0; qt < 2; ++qt) {
        const __hip_bfloat16* qp = Qb + (size_t)(q0 + w * 32 + qt * 16 + l15) * Dk + lg * 8;
        aq[qt][0].u = *(const uint4*)qp;
        aq[qt][1].u = *(const uint4*)(qp + 32);
    }

    f32x4 o[2][4];     // [qt][dt]: C row=q(lg*4+i), col=d(l15)
    f32x4 o4[2];       // l accumulator, col 0
    #pragma unroll
    for (int qt = 0; qt < 2; ++qt) {
        o4[qt] = {0.f, 0.f, 0.f, 0.f};
        #pragma unroll
        for (int dt = 0; dt < 4; ++dt) o[qt][dt] = {0.f, 0.f, 0.f, 0.f};
    }

    __hip_bfloat16* Pw = Ps + (w * 32) * PST;   // wave-private 32 rows

    for (int t = 0; t < Sn / 64; ++t) {
        stage_tile<64, 4>(Kb + (size_t)t * 64 * Dk, Dk, Ks, w, lane);
        stage_tile<64, 4>(Vb + t * 64, Sn, Vts, w, lane);
        __syncthreads();   // loads drained; tile readable by all waves

        // S^T = K·Q'^T; P = exp2(S'); store P[q][key] packed b64
        U16 kf[4][2];
        #pragma unroll
        for (int kt = 0; kt < 4; ++kt) {
            int r = (kt * 16 + l15) * 64;
            kf[kt][0].u = *(const uint4*)&Ks[r + coff0];
            kf[kt][1].u = *(const uint4*)&Ks[r + coff1];
        }
        #pragma unroll
        for (int kt = 0; kt < 4; ++kt)
            #pragma unroll
            for (int qt = 0; qt < 2; ++qt) {
                f32x4 s = {0.f, 0.f, 0.f, 0.f};
                s = __builtin_amdgcn_mfma_f32_16x16x32_bf16(kf[kt][0].v, aq[qt][0].v, s, 0, 0, 0);
                s = __builtin_amdgcn_mfma_f32_16x16x32_bf16(kf[kt][1].v, aq[qt][1].v, s, 0, 0, 0);
                U8 pk;
                pk.h2[0] = __float22bfloat162_rn({exp2f(s[0]), exp2f(s[1])});
                pk.h2[1] = __float22bfloat162_rn({exp2f(s[2]), exp2f(s[3])});
                *(uint2*)&Pw[(qt * 16 + l15) * PST + kt * 16 + lg * 4] = pk.u;
            }

        // PV + l (P rows wave-private: no barrier)
        U16 pf[2][2], vf[4][2];
        #pragma unroll
        for (int qt = 0; qt < 2; ++qt) {
            const __hip_bfloat16* pr = &Pw[(qt * 16 + l15) * PST + lg * 8];
            pf[qt][0].u = *(const uint4*)pr;
            pf[qt][1].u = *(const uint4*)(pr + 32);
        }
        #pragma unroll
        for (int dt = 0; dt < 4; ++dt) {
            int r = (dt * 16 + l15) * 64;
            vf[dt][0].u = *(const uint4*)&Vts[r + coff0];
            vf[dt][1].u = *(const uint4*)&Vts[r + coff1];
        }
        #pragma unroll
        for (int qt = 0; qt < 2; ++qt) {
            #pragma unroll
            for (int dt = 0; dt < 4; ++dt) {
                o[qt][dt] = __builtin_amdgcn_mfma_f32_16x16x32_bf16(pf[qt][0].v, vf[dt][0].v, o[qt][dt], 0, 0, 0);
                o[qt][dt] = __builtin_amdgcn_mfma_f32_16x16x32_bf16(pf[qt][1].v, vf[dt][1].v, o[qt][dt], 0, 0, 0);
            }
            o4[qt] = __builtin_amdgcn_mfma_f32_16x16x32_bf16(pf[qt][0].v, onesf.v, o4[qt], 0, 0, 0);
            o4[qt] = __builtin_amdgcn_mfma_f32_16x16x32_bf16(pf[qt][1].v, onesf.v, o4[qt], 0, 0, 0);
        }
        __syncthreads();   // all reads of Ks/Vts done before next restage
    }

    // l[q=lg*4+i] lives in lane lg*16 (l15==0); broadcast within lg group
    float linv[2][4];
    #pragma unroll
    for (int qt = 0; qt < 2; ++qt)
        #pragma unroll
        for (int i = 0; i < 4; ++i)
            linv[qt][i] = 1.f / __shfl(o4[qt][i], lane & 48, 64);

    int b_ = bh >> 4, h_ = bh & (Hn - 1);
    #pragma unroll
    for (int qt = 0; qt < 2; ++qt)
        #pragma unroll
        for (int i = 0; i < 4; ++i) {
            int sr = q0 + w * 32 + qt * 16 + lg * 4 + i;
            __hip_bfloat16* xp = X + ((size_t)(b_ * Sn + sr)) * En + h_ * Dk + l15;
            #pragma unroll
            for (int dt = 0; dt < 4; ++dt)
                xp[dt * 16] = __float2bfloat16(o[qt][dt][i] * linv[qt][i]);
        }
}

extern "C" void kernel_launch(void* const* d_in, const int* in_sizes, int n_in,
                              void* d_out, int out_size, void* d_ws, size_t ws_size,
                              hipStream_t stream)
{
    const float* query = (const float*)d_in[0];
    const float* key   = (const float*)d_in[1];
    const float* value = (const float*)d_in[2];
    const float* Wq = (const float*)d_in[3];
    const float* bq = (const float*)d_in[4];
    const float* Wk = (const float*)d_in[5];
    const float* bk = (const float*)d_in[6];
    const float* Wv = (const float*)d_in[7];
    const float* bv = (const float*)d_in[8];
    const float* Wo = (const float*)d_in[9];
    const float* bo = (const float*)d_in[10];
    float* out = (float*)d_out;

    // ws (bf16): xbuf[4M] | Wbf[4M] | Qw[4M] | Kw[4M] | Vtw[4M] = 40 MB.
    __hip_bfloat16* xbuf = (__hip_bfloat16*)d_ws;
    __hip_bfloat16* Wbf  = xbuf + TSZ;
    __hip_bfloat16* Qw   = Wbf + 4 * WSZ;
    __hip_bfloat16* Kw   = Qw + TSZ;
    __hip_bfloat16* Vtw  = Kw + TSZ;
    __hip_bfloat16* Xw   = xbuf;   // attn out aliases xbuf

    const float QSCALE = 0.125f * 1.44269504f;   // 1/sqrt(Dk) * log2(e)
    dim3 ggrid(64, 8);

    cvt_w<<<dim3(512, 4), 256, 0, stream>>>(Wq, Wk, Wv, Wo, Wbf);
    cvt_x<<<2048, 256, 0, stream>>>(query, xbuf);
    gemm64<1><<<ggrid, 256, 0, stream>>>(xbuf, Wbf, bq, Qw, QSCALE);
    cvt_x<<<2048, 256, 0, stream>>>(key, xbuf);
    gemm64<1><<<ggrid, 256, 0, stream>>>(xbuf, Wbf + WSZ, bk, Kw, 1.0f);
    cvt_x<<<2048, 256, 0, stream>>>(value, xbuf);
    gemm64<2><<<ggrid, 256, 0, stream>>>(xbuf, Wbf + 2 * WSZ, bv, Vtw, 1.0f);
    attn<<<dim3(Sn / 128, 32), 256, 0, stream>>>(Qw, Kw, Vtw, Xw);
    gemm64<0><<<ggrid, 256, 0, stream>>>(Xw, Wbf + 3 * WSZ, bo, out, 1.0f);
}